// Round 1
// baseline (739.279 us; speedup 1.0000x reference)
//
#include <hip/hip_runtime.h>

#define N_NODES 50000
#define N_EDGES 800000
#define E_TOT   850000      // + self loops
#define IN0     128
#define HID     96
#define NUM_GRAPHS 64

__device__ __forceinline__ float leaky(float x, float s) { return x > 0.f ? x : s * x; }

// ---------------- CSR build ----------------
__global__ void count_deg(const int* __restrict__ dst, int* __restrict__ deg) {
    int e = blockIdx.x * blockDim.x + threadIdx.x;
    if (e >= E_TOT) return;
    int d = (e < N_EDGES) ? dst[e] : (e - N_EDGES);   // appended self loops
    atomicAdd(&deg[d], 1);
}

__global__ void scan_deg(const int* __restrict__ deg, int* __restrict__ offs) {
    __shared__ int part[1024];
    const int n = N_NODES;
    int t = threadIdx.x;
    int chunk = (n + 1023) / 1024;
    int lo = t * chunk, hi = min(lo + chunk, n);
    int s = 0;
    for (int i = lo; i < hi; ++i) s += deg[i];
    part[t] = s;
    __syncthreads();
    for (int off = 1; off < 1024; off <<= 1) {
        int v = (t >= off) ? part[t - off] : 0;
        __syncthreads();
        part[t] += v;
        __syncthreads();
    }
    int base = (t == 0) ? 0 : part[t - 1];
    for (int i = lo; i < hi; ++i) { offs[i] = base; base += deg[i]; }
    if (t == 1023) offs[n] = part[1023];
}

__global__ void scatter_edges(const int* __restrict__ src, const int* __restrict__ dst,
                              const int* __restrict__ offs, int* __restrict__ cursor,
                              int* __restrict__ csr) {
    int e = blockIdx.x * blockDim.x + threadIdx.x;
    if (e >= E_TOT) return;
    int s, d;
    if (e < N_EDGES) { s = src[e]; d = dst[e]; }
    else             { s = e - N_EDGES; d = s; }
    int pos = offs[d] + atomicAdd(&cursor[d], 1);
    csr[pos] = s;
}

// ---------------- fused GEMM + attention logits ----------------
// h = X @ W  (IN x 96), alpha_s = h . a_src, alpha_d = h . a_dst
template <int IN>
__global__ __launch_bounds__(256) void gemm_alpha(
    const float* __restrict__ X, const float* __restrict__ W,
    const float* __restrict__ asrc, const float* __restrict__ adst,
    float* __restrict__ H, float* __restrict__ As, float* __restrict__ Ad) {
    __shared__ float Ws[IN * HID];
    __shared__ float Xs[32 * IN];
    int t = threadIdx.x;
    int rowBase = blockIdx.x * 32;
    for (int idx = t; idx < IN * HID; idx += 256) Ws[idx] = W[idx];
    for (int idx = t; idx < 32 * IN; idx += 256) {
        int r = idx / IN, c = idx - r * IN;
        int gr = rowBase + r;
        Xs[idx] = (gr < N_NODES) ? X[gr * IN + c] : 0.f;
    }
    __syncthreads();
    int r = t >> 5;          // 0..7 (row subgroup)
    int lane = t & 31;
    int c = lane * 3;        // 32 lanes x 3 cols = 96
    float acc[4][3];
#pragma unroll
    for (int i = 0; i < 4; ++i)
#pragma unroll
        for (int j = 0; j < 3; ++j) acc[i][j] = 0.f;
#pragma unroll 4
    for (int k = 0; k < IN; ++k) {
        float w0 = Ws[k * HID + c], w1 = Ws[k * HID + c + 1], w2 = Ws[k * HID + c + 2];
#pragma unroll
        for (int i = 0; i < 4; ++i) {
            float xv = Xs[(r + 8 * i) * IN + k];
            acc[i][0] += xv * w0; acc[i][1] += xv * w1; acc[i][2] += xv * w2;
        }
    }
    float a0 = asrc[c], a1 = asrc[c + 1], a2 = asrc[c + 2];
    float d0 = adst[c], d1 = adst[c + 1], d2 = adst[c + 2];
#pragma unroll
    for (int i = 0; i < 4; ++i) {
        int row = rowBase + r + 8 * i;
        if (row < N_NODES) {   // uniform across the 32-lane group
            H[row * HID + c]     = acc[i][0];
            H[row * HID + c + 1] = acc[i][1];
            H[row * HID + c + 2] = acc[i][2];
            float ps = acc[i][0] * a0 + acc[i][1] * a1 + acc[i][2] * a2;
            float pd = acc[i][0] * d0 + acc[i][1] * d1 + acc[i][2] * d2;
#pragma unroll
            for (int m = 16; m >= 1; m >>= 1) {
                ps += __shfl_xor(ps, m);
                pd += __shfl_xor(pd, m);
            }
            if (lane == 0) { As[row] = ps; Ad[row] = pd; }
        }
    }
}

// ---------------- CSR softmax-aggregate ----------------
// one 32-lane team per destination node; lane owns 3 of 96 features
__global__ __launch_bounds__(256) void aggregate(
    const float* __restrict__ H, const float* __restrict__ As, const float* __restrict__ Ad,
    const int* __restrict__ offs, const int* __restrict__ csr,
    const float* __restrict__ bias, float* __restrict__ Hout, int apply_leaky) {
    int team = (blockIdx.x * blockDim.x + threadIdx.x) >> 5;   // == node, grid sized exactly
    int lane = threadIdx.x & 31;
    int srcBase = threadIdx.x & 32;   // which half of the wave this team occupies
    int n = team;
    int start = offs[n], end = offs[n + 1];
    float ad = Ad[n];
    // phase A: neighborhood max of leaky(att logit)
    float m = -1e30f;
    for (int i = start + lane; i < end; i += 32) {
        int s = csr[i];
        m = fmaxf(m, leaky(As[s] + ad, 0.2f));
    }
#pragma unroll
    for (int w = 16; w >= 1; w >>= 1) m = fmaxf(m, __shfl_xor(m, w));
    // phase B: exp, denom, and weighted gather-accumulate
    float acc0 = 0.f, acc1 = 0.f, acc2 = 0.f, denom = 0.f;
    int c = lane * 3;
    for (int base = start; base < end; base += 32) {
        int i = base + lane;
        bool valid = i < end;
        int s = valid ? csr[i] : 0;
        float ex = 0.f;
        if (valid) ex = __expf(leaky(As[s] + ad, 0.2f) - m);
        denom += ex;
        int cnt = min(32, end - base);
        for (int j = 0; j < cnt; ++j) {
            float bex = __shfl(ex, srcBase + j);
            int   bs  = __shfl(s,  srcBase + j);
            const float* hp = H + bs * HID + c;
            acc0 += bex * hp[0];
            acc1 += bex * hp[1];
            acc2 += bex * hp[2];
        }
    }
#pragma unroll
    for (int w = 16; w >= 1; w >>= 1) denom += __shfl_xor(denom, w);
    float inv = 1.f / (denom + 1e-16f);
    float o0 = acc0 * inv + bias[c];
    float o1 = acc1 * inv + bias[c + 1];
    float o2 = acc2 * inv + bias[c + 2];
    if (apply_leaky) { o0 = leaky(o0, 0.01f); o1 = leaky(o1, 0.01f); o2 = leaky(o2, 0.01f); }
    Hout[n * HID + c]     = o0;
    Hout[n * HID + c + 1] = o1;
    Hout[n * HID + c + 2] = o2;
}

// ---------------- global mean pool ----------------
__global__ void pool_count(const int* __restrict__ batch, float* __restrict__ counts) {
    int n = blockIdx.x * blockDim.x + threadIdx.x;
    if (n < N_NODES) atomicAdd(&counts[batch[n]], 1.f);
}

__global__ __launch_bounds__(256) void pool_sum(
    const float* __restrict__ H, const int* __restrict__ batch, float* __restrict__ out) {
    __shared__ float acc[NUM_GRAPHS * HID];   // 24 KB
    int t = threadIdx.x;
    for (int i = t; i < NUM_GRAPHS * HID; i += 256) acc[i] = 0.f;
    __syncthreads();
    int blockStart = blockIdx.x * 256;
    int team = t >> 5, lane = t & 31, c = lane * 3;
    for (int k = 0; k < 32; ++k) {
        int n = blockStart + team * 32 + k;
        if (n < N_NODES) {
            int g = batch[n];
            const float* hp = H + n * HID + c;
            atomicAdd(&acc[g * HID + c],     hp[0]);
            atomicAdd(&acc[g * HID + c + 1], hp[1]);
            atomicAdd(&acc[g * HID + c + 2], hp[2]);
        }
    }
    __syncthreads();
    int firstN = min(blockStart, N_NODES - 1);
    int lastN  = min(blockStart + 255, N_NODES - 1);
    int gmin = batch[firstN], gmax = batch[lastN];   // batch is sorted
    int span = (gmax - gmin + 1) * HID;
    for (int i = t; i < span; i += 256)
        atomicAdd(&out[gmin * HID + i], acc[gmin * HID + i]);
}

__global__ void pool_div(float* __restrict__ out, const float* __restrict__ counts) {
    int i = blockIdx.x * blockDim.x + threadIdx.x;
    if (i < NUM_GRAPHS * HID) out[i] /= fmaxf(counts[i / HID], 1.f);
}

// ---------------- launch ----------------
extern "C" void kernel_launch(void* const* d_in, const int* in_sizes, int n_in,
                              void* d_out, int out_size, void* d_ws, size_t ws_size,
                              hipStream_t stream) {
    const float* x     = (const float*)d_in[0];
    const int*   ei    = (const int*)d_in[1];
    const int*   srcI  = ei;
    const int*   dstI  = ei + N_EDGES;
    const int*   batch = (const int*)d_in[2];
    const float* W1 = (const float*)d_in[3],  *as1 = (const float*)d_in[4],
               * ad1 = (const float*)d_in[5], *b1  = (const float*)d_in[6];
    const float* W2 = (const float*)d_in[7],  *as2 = (const float*)d_in[8],
               * ad2 = (const float*)d_in[9], *b2  = (const float*)d_in[10];
    const float* W3 = (const float*)d_in[11], *as3 = (const float*)d_in[12],
               * ad3 = (const float*)d_in[13], *b3 = (const float*)d_in[14];
    float* out = (float*)d_out;

    // workspace layout (~43 MB)
    char* p = (char*)d_ws;
    float* h0 = (float*)p;  p += (size_t)N_NODES * HID * 4;
    float* h1 = (float*)p;  p += (size_t)N_NODES * HID * 4;
    float* As = (float*)p;  p += (size_t)N_NODES * 4;
    float* Ad = (float*)p;  p += (size_t)N_NODES * 4;
    float* counts = (float*)p; p += 256;
    int* deg    = (int*)p;  p += (size_t)N_NODES * 4;
    int* offs   = (int*)p;  p += (size_t)(N_NODES + 1) * 4 + 252; // keep alignment
    int* cursor = (int*)p;  p += (size_t)N_NODES * 4;
    int* csr    = (int*)p;  p += (size_t)E_TOT * 4;

    hipMemsetAsync(deg,    0, (size_t)N_NODES * 4, stream);
    hipMemsetAsync(cursor, 0, (size_t)N_NODES * 4, stream);
    hipMemsetAsync(counts, 0, 64 * 4, stream);
    hipMemsetAsync(out,    0, (size_t)NUM_GRAPHS * HID * 4, stream);

    int eb = (E_TOT + 255) / 256;
    count_deg<<<eb, 256, 0, stream>>>(dstI, deg);
    scan_deg<<<1, 1024, 0, stream>>>(deg, offs);
    scatter_edges<<<eb, 256, 0, stream>>>(srcI, dstI, offs, cursor, csr);

    int gemmGrid = (N_NODES + 31) / 32;
    int aggGrid  = (N_NODES * 32) / 256;   // exact: 6250

    // layer 1
    gemm_alpha<IN0><<<gemmGrid, 256, 0, stream>>>(x, W1, as1, ad1, h0, As, Ad);
    aggregate<<<aggGrid, 256, 0, stream>>>(h0, As, Ad, offs, csr, b1, h1, 1);
    // layer 2
    gemm_alpha<HID><<<gemmGrid, 256, 0, stream>>>(h1, W2, as2, ad2, h0, As, Ad);
    aggregate<<<aggGrid, 256, 0, stream>>>(h0, As, Ad, offs, csr, b2, h1, 1);
    // layer 3
    gemm_alpha<HID><<<gemmGrid, 256, 0, stream>>>(h1, W3, as3, ad3, h0, As, Ad);
    aggregate<<<aggGrid, 256, 0, stream>>>(h0, As, Ad, offs, csr, b3, h1, 0);

    // mean pool
    pool_count<<<(N_NODES + 255) / 256, 256, 0, stream>>>(batch, counts);
    pool_sum<<<(N_NODES + 255) / 256, 256, 0, stream>>>(h1, batch, out);
    pool_div<<<(NUM_GRAPHS * HID + 255) / 256, 256, 0, stream>>>(out, counts);
}

// Round 2
// 524.380 us; speedup vs baseline: 1.4098x; 1.4098x over previous
//
#include <hip/hip_runtime.h>

#define N_NODES 50000
#define N_EDGES 800000
#define E_TOT   850000      // + self loops
#define IN0     128
#define HID     96
#define NUM_GRAPHS 64

__device__ __forceinline__ float leaky(float x, float s) { return x > 0.f ? x : s * x; }

// ---------------- CSR build ----------------
__global__ void count_deg(const int* __restrict__ dst, int* __restrict__ deg) {
    int e = blockIdx.x * blockDim.x + threadIdx.x;
    if (e >= E_TOT) return;
    int d = (e < N_EDGES) ? dst[e] : (e - N_EDGES);   // appended self loops
    atomicAdd(&deg[d], 1);
}

__global__ void scan_deg(const int* __restrict__ deg, int* __restrict__ offs) {
    __shared__ int part[1024];
    const int n = N_NODES;
    int t = threadIdx.x;
    int chunk = (n + 1023) / 1024;
    int lo = t * chunk, hi = min(lo + chunk, n);
    int s = 0;
    for (int i = lo; i < hi; ++i) s += deg[i];
    part[t] = s;
    __syncthreads();
    for (int off = 1; off < 1024; off <<= 1) {
        int v = (t >= off) ? part[t - off] : 0;
        __syncthreads();
        part[t] += v;
        __syncthreads();
    }
    int base = (t == 0) ? 0 : part[t - 1];
    for (int i = lo; i < hi; ++i) { offs[i] = base; base += deg[i]; }
    if (t == 1023) offs[n] = part[1023];
}

__global__ void scatter_edges(const int* __restrict__ src, const int* __restrict__ dst,
                              const int* __restrict__ offs, int* __restrict__ cursor,
                              int* __restrict__ csr) {
    int e = blockIdx.x * blockDim.x + threadIdx.x;
    if (e >= E_TOT) return;
    int s, d;
    if (e < N_EDGES) { s = src[e]; d = dst[e]; }
    else             { s = e - N_EDGES; d = s; }
    int pos = offs[d] + atomicAdd(&cursor[d], 1);
    csr[pos] = s;
}

// ---------------- fused GEMM + attention logits ----------------
template <int IN>
__global__ __launch_bounds__(256) void gemm_alpha(
    const float* __restrict__ X, const float* __restrict__ W,
    const float* __restrict__ asrc, const float* __restrict__ adst,
    float* __restrict__ H, float* __restrict__ As, float* __restrict__ Ad) {
    __shared__ float Ws[IN * HID];
    __shared__ float Xs[32 * IN];
    int t = threadIdx.x;
    int rowBase = blockIdx.x * 32;
    for (int idx = t; idx < IN * HID; idx += 256) Ws[idx] = W[idx];
    for (int idx = t; idx < 32 * IN; idx += 256) {
        int r = idx / IN, c = idx - r * IN;
        int gr = rowBase + r;
        Xs[idx] = (gr < N_NODES) ? X[gr * IN + c] : 0.f;
    }
    __syncthreads();
    int r = t >> 5;          // 0..7
    int lane = t & 31;
    int c = lane * 3;
    float acc[4][3];
#pragma unroll
    for (int i = 0; i < 4; ++i)
#pragma unroll
        for (int j = 0; j < 3; ++j) acc[i][j] = 0.f;
#pragma unroll 4
    for (int k = 0; k < IN; ++k) {
        float w0 = Ws[k * HID + c], w1 = Ws[k * HID + c + 1], w2 = Ws[k * HID + c + 2];
#pragma unroll
        for (int i = 0; i < 4; ++i) {
            float xv = Xs[(r + 8 * i) * IN + k];
            acc[i][0] += xv * w0; acc[i][1] += xv * w1; acc[i][2] += xv * w2;
        }
    }
    float a0 = asrc[c], a1 = asrc[c + 1], a2 = asrc[c + 2];
    float d0 = adst[c], d1 = adst[c + 1], d2 = adst[c + 2];
#pragma unroll
    for (int i = 0; i < 4; ++i) {
        int row = rowBase + r + 8 * i;
        if (row < N_NODES) {
            H[row * HID + c]     = acc[i][0];
            H[row * HID + c + 1] = acc[i][1];
            H[row * HID + c + 2] = acc[i][2];
            float ps = acc[i][0] * a0 + acc[i][1] * a1 + acc[i][2] * a2;
            float pd = acc[i][0] * d0 + acc[i][1] * d1 + acc[i][2] * d2;
#pragma unroll
            for (int m = 16; m >= 1; m >>= 1) {
                ps += __shfl_xor(ps, m);
                pd += __shfl_xor(pd, m);
            }
            if (lane == 0) { As[row] = ps; Ad[row] = pd; }
        }
    }
}

// ---------------- CSR softmax-aggregate ----------------
// one 32-lane team per destination node; lane owns 3 of 96 features.
// inner loop unrolled x8: 24 independent gather loads in flight per lane.
__global__ __launch_bounds__(256) void aggregate(
    const float* __restrict__ H, const float* __restrict__ As, const float* __restrict__ Ad,
    const int* __restrict__ offs, const int* __restrict__ csr,
    const float* __restrict__ bias, float* __restrict__ Hout, int apply_leaky) {
    int team = (blockIdx.x * blockDim.x + threadIdx.x) >> 5;   // == node
    int lane = threadIdx.x & 31;
    int half = threadIdx.x & 32;   // wave64 half base for shfl
    int start = offs[team], end = offs[team + 1];
    float ad = Ad[team];
    // phase A: neighborhood max
    float m = -1e30f;
    for (int i = start + lane; i < end; i += 32) {
        int s = csr[i];
        m = fmaxf(m, leaky(As[s] + ad, 0.2f));
    }
#pragma unroll
    for (int w = 16; w >= 1; w >>= 1) m = fmaxf(m, __shfl_xor(m, w));
    // phase B
    float acc0 = 0.f, acc1 = 0.f, acc2 = 0.f, denom = 0.f;
    int c = lane * 3;
    for (int base = start; base < end; base += 32) {
        int i = base + lane;
        bool valid = i < end;
        int s = valid ? csr[i] : 0;
        float ex = 0.f;
        if (valid) ex = __expf(leaky(As[s] + ad, 0.2f) - m);
        denom += ex;
        int cnt = min(32, end - base);
        int j = 0;
        for (; j + 8 <= cnt; j += 8) {
            float e[8]; int ss[8];
#pragma unroll
            for (int q = 0; q < 8; ++q) {
                e[q]  = __shfl(ex, half + j + q);
                ss[q] = __shfl(s,  half + j + q);
            }
            float v0[8], v1[8], v2[8];
#pragma unroll
            for (int q = 0; q < 8; ++q) {
                const float* p = H + (size_t)ss[q] * HID + c;
                v0[q] = p[0]; v1[q] = p[1]; v2[q] = p[2];
            }
#pragma unroll
            for (int q = 0; q < 8; ++q) {
                acc0 += e[q] * v0[q]; acc1 += e[q] * v1[q]; acc2 += e[q] * v2[q];
            }
        }
        for (; j + 4 <= cnt; j += 4) {
            float e[4]; int ss[4];
#pragma unroll
            for (int q = 0; q < 4; ++q) {
                e[q]  = __shfl(ex, half + j + q);
                ss[q] = __shfl(s,  half + j + q);
            }
            float v0[4], v1[4], v2[4];
#pragma unroll
            for (int q = 0; q < 4; ++q) {
                const float* p = H + (size_t)ss[q] * HID + c;
                v0[q] = p[0]; v1[q] = p[1]; v2[q] = p[2];
            }
#pragma unroll
            for (int q = 0; q < 4; ++q) {
                acc0 += e[q] * v0[q]; acc1 += e[q] * v1[q]; acc2 += e[q] * v2[q];
            }
        }
        for (; j < cnt; ++j) {
            float bex = __shfl(ex, half + j);
            int   bs  = __shfl(s,  half + j);
            const float* hp = H + (size_t)bs * HID + c;
            acc0 += bex * hp[0]; acc1 += bex * hp[1]; acc2 += bex * hp[2];
        }
    }
#pragma unroll
    for (int w = 16; w >= 1; w >>= 1) denom += __shfl_xor(denom, w);
    float inv = 1.f / (denom + 1e-16f);
    float o0 = acc0 * inv + bias[c];
    float o1 = acc1 * inv + bias[c + 1];
    float o2 = acc2 * inv + bias[c + 2];
    if (apply_leaky) { o0 = leaky(o0, 0.01f); o1 = leaky(o1, 0.01f); o2 = leaky(o2, 0.01f); }
    Hout[team * HID + c]     = o0;
    Hout[team * HID + c + 1] = o1;
    Hout[team * HID + c + 2] = o2;
}

// ---------------- global mean pool (fused count+sum, batch sorted) ----------------
__global__ __launch_bounds__(256) void pool_sum(
    const float* __restrict__ H, const int* __restrict__ batch,
    float* __restrict__ sums, float* __restrict__ counts) {
    int team = (blockIdx.x * blockDim.x + threadIdx.x) >> 5;
    int lane = threadIdx.x & 31;
    int c = lane * 3;
    int n0 = team * 32;
    if (n0 >= N_NODES) return;
    int n1 = min(n0 + 32, N_NODES);
    float a0 = 0.f, a1 = 0.f, a2 = 0.f;
    int cur = batch[n0], runlen = 0;
    for (int n = n0; n < n1; ++n) {
        int g = batch[n];
        if (g != cur) {   // uniform across team (same n for all lanes)
            atomicAdd(&sums[cur * HID + c],     a0);
            atomicAdd(&sums[cur * HID + c + 1], a1);
            atomicAdd(&sums[cur * HID + c + 2], a2);
            if (lane == 0) atomicAdd(&counts[cur], (float)runlen);
            a0 = a1 = a2 = 0.f; cur = g; runlen = 0;
        }
        const float* hp = H + (size_t)n * HID + c;
        a0 += hp[0]; a1 += hp[1]; a2 += hp[2];
        ++runlen;
    }
    atomicAdd(&sums[cur * HID + c],     a0);
    atomicAdd(&sums[cur * HID + c + 1], a1);
    atomicAdd(&sums[cur * HID + c + 2], a2);
    if (lane == 0) atomicAdd(&counts[cur], (float)runlen);
}

__global__ void finalize(const float* __restrict__ sums, const float* __restrict__ counts,
                         float* __restrict__ out) {
    int i = blockIdx.x * blockDim.x + threadIdx.x;
    if (i < NUM_GRAPHS * HID) out[i] = sums[i] / fmaxf(counts[i / HID], 1.f);
}

// ---------------- launch ----------------
extern "C" void kernel_launch(void* const* d_in, const int* in_sizes, int n_in,
                              void* d_out, int out_size, void* d_ws, size_t ws_size,
                              hipStream_t stream) {
    const float* x     = (const float*)d_in[0];
    const int*   ei    = (const int*)d_in[1];
    const int*   srcI  = ei;
    const int*   dstI  = ei + N_EDGES;
    const int*   batch = (const int*)d_in[2];
    const float* W1 = (const float*)d_in[3],  *as1 = (const float*)d_in[4],
               * ad1 = (const float*)d_in[5], *b1  = (const float*)d_in[6];
    const float* W2 = (const float*)d_in[7],  *as2 = (const float*)d_in[8],
               * ad2 = (const float*)d_in[9], *b2  = (const float*)d_in[10];
    const float* W3 = (const float*)d_in[11], *as3 = (const float*)d_in[12],
               * ad3 = (const float*)d_in[13], *b3 = (const float*)d_in[14];
    float* out = (float*)d_out;

    // workspace layout
    char* p = (char*)d_ws;
    float* h0 = (float*)p;  p += (size_t)N_NODES * HID * 4;
    float* h1 = (float*)p;  p += (size_t)N_NODES * HID * 4;
    float* As = (float*)p;  p += (size_t)N_NODES * 4;
    float* Ad = (float*)p;  p += (size_t)N_NODES * 4;
    int* offs = (int*)p;    p += (size_t)(N_NODES + 4) * 4;
    int* csr  = (int*)p;    p += (size_t)E_TOT * 4;
    // contiguous zero-region: sums | counts | deg | cursor
    char* zbase = p;
    float* sums   = (float*)p; p += (size_t)NUM_GRAPHS * HID * 4;
    float* counts = (float*)p; p += (size_t)NUM_GRAPHS * 4;
    int* deg    = (int*)p;  p += (size_t)N_NODES * 4;
    int* cursor = (int*)p;  p += (size_t)N_NODES * 4;
    size_t zbytes = (size_t)(p - zbase);

    hipMemsetAsync(zbase, 0, zbytes, stream);

    int eb = (E_TOT + 255) / 256;
    count_deg<<<eb, 256, 0, stream>>>(dstI, deg);
    scan_deg<<<1, 1024, 0, stream>>>(deg, offs);
    scatter_edges<<<eb, 256, 0, stream>>>(srcI, dstI, offs, cursor, csr);

    int gemmGrid = (N_NODES + 31) / 32;
    int aggGrid  = (N_NODES * 32) / 256;   // exact: 6250

    // layer 1
    gemm_alpha<IN0><<<gemmGrid, 256, 0, stream>>>(x, W1, as1, ad1, h0, As, Ad);
    aggregate<<<aggGrid, 256, 0, stream>>>(h0, As, Ad, offs, csr, b1, h1, 1);
    // layer 2
    gemm_alpha<HID><<<gemmGrid, 256, 0, stream>>>(h1, W2, as2, ad2, h0, As, Ad);
    aggregate<<<aggGrid, 256, 0, stream>>>(h0, As, Ad, offs, csr, b2, h1, 1);
    // layer 3
    gemm_alpha<HID><<<gemmGrid, 256, 0, stream>>>(h1, W3, as3, ad3, h0, As, Ad);
    aggregate<<<aggGrid, 256, 0, stream>>>(h0, As, Ad, offs, csr, b3, h1, 0);

    // mean pool
    int teams = (N_NODES + 31) / 32;
    pool_sum<<<(teams * 32 + 255) / 256, 256, 0, stream>>>(h1, batch, sums, counts);
    finalize<<<(NUM_GRAPHS * HID + 255) / 256, 256, 0, stream>>>(sums, counts, out);
}

// Round 5
// 454.968 us; speedup vs baseline: 1.6249x; 1.1526x over previous
//
#include <hip/hip_runtime.h>

#define N_NODES 50000
#define N_EDGES 800000
#define E_TOT   850000      // + self loops
#define IN0     128
#define HID     96
#define NUM_GRAPHS 64
#define NB      ((N_NODES + 1023) / 1024)   // 49 scan blocks

__device__ __forceinline__ float leaky(float x, float s) { return x > 0.f ? x : s * x; }

// ---------------- CSR build ----------------
__global__ void count_deg(const int* __restrict__ dst, int* __restrict__ deg) {
    int e = blockIdx.x * blockDim.x + threadIdx.x;
    if (e >= E_TOT) return;
    int d = (e < N_EDGES) ? dst[e] : (e - N_EDGES);   // appended self loops
    atomicAdd(&deg[d], 1);
}

// 3-kernel multi-block exclusive scan of deg -> offs
__global__ __launch_bounds__(256) void block_sums(const int* __restrict__ deg, int* __restrict__ bsum) {
    int b = blockIdx.x, t = threadIdx.x;
    int base = b * 1024 + t * 4;
    int s = 0;
    if (base + 3 < N_NODES) {
        int4 v = *(const int4*)(deg + base);
        s = v.x + v.y + v.z + v.w;
    } else {
        for (int k = 0; k < 4; ++k) if (base + k < N_NODES) s += deg[base + k];
    }
#pragma unroll
    for (int w = 32; w >= 1; w >>= 1) s += __shfl_xor(s, w);
    __shared__ int ws[4];
    if ((t & 63) == 0) ws[t >> 6] = s;
    __syncthreads();
    if (t == 0) bsum[b] = ws[0] + ws[1] + ws[2] + ws[3];
}

__global__ void scan_partials(const int* __restrict__ bsum, int* __restrict__ excl, int* __restrict__ offs) {
    int t = threadIdx.x;   // 64 threads
    int v = (t < NB) ? bsum[t] : 0;
    int incl = v;
#pragma unroll
    for (int d = 1; d < 64; d <<= 1) {
        int u = __shfl_up(incl, d);
        if (t >= d) incl += u;
    }
    if (t < NB) excl[t] = incl - v;
    if (t == 0) offs[N_NODES] = E_TOT;
}

__global__ __launch_bounds__(256) void write_offs(const int* __restrict__ deg,
                                                  const int* __restrict__ excl,
                                                  int* __restrict__ offs) {
    __shared__ int sh[256];
    int b = blockIdx.x, t = threadIdx.x;
    int base = b * 1024 + t * 4;
    int d0 = 0, d1 = 0, d2 = 0, d3 = 0;
    if (base + 3 < N_NODES) {
        int4 v = *(const int4*)(deg + base);
        d0 = v.x; d1 = v.y; d2 = v.z; d3 = v.w;
    } else {
        if (base     < N_NODES) d0 = deg[base];
        if (base + 1 < N_NODES) d1 = deg[base + 1];
        if (base + 2 < N_NODES) d2 = deg[base + 2];
    }
    int tsum = d0 + d1 + d2 + d3;
    sh[t] = tsum;
    __syncthreads();
    for (int off = 1; off < 256; off <<= 1) {
        int u = (t >= off) ? sh[t - off] : 0;
        __syncthreads();
        sh[t] += u;
        __syncthreads();
    }
    int ebase = excl[b] + sh[t] - tsum;
    if (base + 3 < N_NODES) {
        int4 o; o.x = ebase; o.y = ebase + d0; o.z = ebase + d0 + d1; o.w = ebase + d0 + d1 + d2;
        *(int4*)(offs + base) = o;
    } else {
        if (base     < N_NODES) offs[base]     = ebase;
        if (base + 1 < N_NODES) offs[base + 1] = ebase + d0;
        if (base + 2 < N_NODES) offs[base + 2] = ebase + d0 + d1;
    }
}

__global__ void scatter_edges(const int* __restrict__ src, const int* __restrict__ dst,
                              const int* __restrict__ offs, int* __restrict__ cursor,
                              int* __restrict__ csr) {
    int e = blockIdx.x * blockDim.x + threadIdx.x;
    if (e >= E_TOT) return;
    int s, d;
    if (e < N_EDGES) { s = src[e]; d = dst[e]; }
    else             { s = e - N_EDGES; d = s; }
    int pos = offs[d] + atomicAdd(&cursor[d], 1);
    csr[pos] = s;
}

// ---------------- fused GEMM + attention logits ----------------
template <int IN>
__global__ __launch_bounds__(256) void gemm_alpha(
    const float* __restrict__ X, const float* __restrict__ W,
    const float* __restrict__ asrc, const float* __restrict__ adst,
    float* __restrict__ H, float* __restrict__ As, float* __restrict__ Ad) {
    __shared__ float Ws[IN * HID];
    __shared__ float Xs[32 * IN];
    int t = threadIdx.x;
    int rowBase = blockIdx.x * 32;
    for (int idx = t; idx < IN * HID; idx += 256) Ws[idx] = W[idx];
    for (int idx = t; idx < 32 * IN; idx += 256) {
        int r = idx / IN, c = idx - r * IN;
        int gr = rowBase + r;
        Xs[idx] = (gr < N_NODES) ? X[gr * IN + c] : 0.f;
    }
    __syncthreads();
    int r = t >> 5;          // 0..7
    int lane = t & 31;
    int c = lane * 3;
    float acc[4][3];
#pragma unroll
    for (int i = 0; i < 4; ++i)
#pragma unroll
        for (int j = 0; j < 3; ++j) acc[i][j] = 0.f;
#pragma unroll 4
    for (int k = 0; k < IN; ++k) {
        float w0 = Ws[k * HID + c], w1 = Ws[k * HID + c + 1], w2 = Ws[k * HID + c + 2];
#pragma unroll
        for (int i = 0; i < 4; ++i) {
            float xv = Xs[(r + 8 * i) * IN + k];
            acc[i][0] += xv * w0; acc[i][1] += xv * w1; acc[i][2] += xv * w2;
        }
    }
    float a0 = asrc[c], a1 = asrc[c + 1], a2 = asrc[c + 2];
    float d0 = adst[c], d1 = adst[c + 1], d2 = adst[c + 2];
#pragma unroll
    for (int i = 0; i < 4; ++i) {
        int row = rowBase + r + 8 * i;
        if (row < N_NODES) {
            H[row * HID + c]     = acc[i][0];
            H[row * HID + c + 1] = acc[i][1];
            H[row * HID + c + 2] = acc[i][2];
            float ps = acc[i][0] * a0 + acc[i][1] * a1 + acc[i][2] * a2;
            float pd = acc[i][0] * d0 + acc[i][1] * d1 + acc[i][2] * d2;
#pragma unroll
            for (int m = 16; m >= 1; m >>= 1) {
                ps += __shfl_xor(ps, m);
                pd += __shfl_xor(pd, m);
            }
            if (lane == 0) { As[row] = ps; Ad[row] = pd; }
        }
    }
}

// ---------------- CSR softmax-aggregate (no max pass; shift by self-loop logit) --------
__global__ __launch_bounds__(256) void aggregate(
    const float* __restrict__ H, const float* __restrict__ As, const float* __restrict__ Ad,
    const int* __restrict__ offs, const int* __restrict__ csr,
    const float* __restrict__ bias, float* __restrict__ Hout, int apply_leaky) {
    int team = (blockIdx.x * blockDim.x + threadIdx.x) >> 5;   // == node
    int lane = threadIdx.x & 31;
    int half = threadIdx.x & 32;   // wave64 half base for shfl
    int start = offs[team], end = offs[team + 1];
    float ad = Ad[team];
    // softmax shift: self-loop logit (free, no gather; denom >= 1)
    float m = leaky(As[team] + ad, 0.2f);
    float acc0 = 0.f, acc1 = 0.f, acc2 = 0.f, denom = 0.f;
    int c = lane * 3;
    for (int base = start; base < end; base += 32) {
        int i = base + lane;
        bool valid = i < end;
        int s = valid ? csr[i] : 0;
        float ex = 0.f;
        if (valid) ex = __expf(leaky(As[s] + ad, 0.2f) - m);
        denom += ex;
        int cnt = min(32, end - base);
        int j = 0;
        for (; j + 8 <= cnt; j += 8) {
            float e[8]; int ss[8];
#pragma unroll
            for (int q = 0; q < 8; ++q) {
                e[q]  = __shfl(ex, half + j + q);
                ss[q] = __shfl(s,  half + j + q);
            }
            float v0[8], v1[8], v2[8];
#pragma unroll
            for (int q = 0; q < 8; ++q) {
                const float* p = H + (size_t)ss[q] * HID + c;
                v0[q] = p[0]; v1[q] = p[1]; v2[q] = p[2];
            }
#pragma unroll
            for (int q = 0; q < 8; ++q) {
                acc0 += e[q] * v0[q]; acc1 += e[q] * v1[q]; acc2 += e[q] * v2[q];
            }
        }
        for (; j + 4 <= cnt; j += 4) {
            float e[4]; int ss[4];
#pragma unroll
            for (int q = 0; q < 4; ++q) {
                e[q]  = __shfl(ex, half + j + q);
                ss[q] = __shfl(s,  half + j + q);
            }
            float v0[4], v1[4], v2[4];
#pragma unroll
            for (int q = 0; q < 4; ++q) {
                const float* p = H + (size_t)ss[q] * HID + c;
                v0[q] = p[0]; v1[q] = p[1]; v2[q] = p[2];
            }
#pragma unroll
            for (int q = 0; q < 4; ++q) {
                acc0 += e[q] * v0[q]; acc1 += e[q] * v1[q]; acc2 += e[q] * v2[q];
            }
        }
        for (; j < cnt; ++j) {
            float bex = __shfl(ex, half + j);
            int   bs  = __shfl(s,  half + j);
            const float* hp = H + (size_t)bs * HID + c;
            acc0 += bex * hp[0]; acc1 += bex * hp[1]; acc2 += bex * hp[2];
        }
    }
#pragma unroll
    for (int w = 16; w >= 1; w >>= 1) denom += __shfl_xor(denom, w);
    float inv = 1.f / (denom + 1e-16f);
    float o0 = acc0 * inv + bias[c];
    float o1 = acc1 * inv + bias[c + 1];
    float o2 = acc2 * inv + bias[c + 2];
    if (apply_leaky) { o0 = leaky(o0, 0.01f); o1 = leaky(o1, 0.01f); o2 = leaky(o2, 0.01f); }
    Hout[team * HID + c]     = o0;
    Hout[team * HID + c + 1] = o1;
    Hout[team * HID + c + 2] = o2;
}

// ---------------- global mean pool (fused count+sum, batch sorted) ----------------
__global__ __launch_bounds__(256) void pool_sum(
    const float* __restrict__ H, const int* __restrict__ batch,
    float* __restrict__ sums, float* __restrict__ counts) {
    int team = (blockIdx.x * blockDim.x + threadIdx.x) >> 5;
    int lane = threadIdx.x & 31;
    int c = lane * 3;
    int n0 = team * 32;
    if (n0 >= N_NODES) return;
    int n1 = min(n0 + 32, N_NODES);
    float a0 = 0.f, a1 = 0.f, a2 = 0.f;
    int cur = batch[n0], runlen = 0;
    for (int n = n0; n < n1; ++n) {
        int g = batch[n];
        if (g != cur) {
            atomicAdd(&sums[cur * HID + c],     a0);
            atomicAdd(&sums[cur * HID + c + 1], a1);
            atomicAdd(&sums[cur * HID + c + 2], a2);
            if (lane == 0) atomicAdd(&counts[cur], (float)runlen);
            a0 = a1 = a2 = 0.f; cur = g; runlen = 0;
        }
        const float* hp = H + (size_t)n * HID + c;
        a0 += hp[0]; a1 += hp[1]; a2 += hp[2];
        ++runlen;
    }
    atomicAdd(&sums[cur * HID + c],     a0);
    atomicAdd(&sums[cur * HID + c + 1], a1);
    atomicAdd(&sums[cur * HID + c + 2], a2);
    if (lane == 0) atomicAdd(&counts[cur], (float)runlen);
}

__global__ void finalize(const float* __restrict__ sums, const float* __restrict__ counts,
                         float* __restrict__ out) {
    int i = blockIdx.x * blockDim.x + threadIdx.x;
    if (i < NUM_GRAPHS * HID) out[i] = sums[i] / fmaxf(counts[i / HID], 1.f);
}

// ---------------- launch ----------------
extern "C" void kernel_launch(void* const* d_in, const int* in_sizes, int n_in,
                              void* d_out, int out_size, void* d_ws, size_t ws_size,
                              hipStream_t stream) {
    const float* x     = (const float*)d_in[0];
    const int*   ei    = (const int*)d_in[1];
    const int*   srcI  = ei;
    const int*   dstI  = ei + N_EDGES;
    const int*   batch = (const int*)d_in[2];
    const float* W1 = (const float*)d_in[3],  *as1 = (const float*)d_in[4],
               * ad1 = (const float*)d_in[5], *b1  = (const float*)d_in[6];
    const float* W2 = (const float*)d_in[7],  *as2 = (const float*)d_in[8],
               * ad2 = (const float*)d_in[9], *b2  = (const float*)d_in[10];
    const float* W3 = (const float*)d_in[11], *as3 = (const float*)d_in[12],
               * ad3 = (const float*)d_in[13], *b3 = (const float*)d_in[14];
    float* out = (float*)d_out;

    // workspace layout (all 16B-aligned by construction)
    char* p = (char*)d_ws;
    float* h0 = (float*)p;  p += (size_t)N_NODES * HID * 4;
    float* h1 = (float*)p;  p += (size_t)N_NODES * HID * 4;
    float* As = (float*)p;  p += (size_t)N_NODES * 4;
    float* Ad = (float*)p;  p += (size_t)N_NODES * 4;
    int* offs = (int*)p;    p += (size_t)(N_NODES + 4) * 4;
    int* csr  = (int*)p;    p += (size_t)E_TOT * 4;
    int* bsum = (int*)p;    p += 64 * 4;
    int* excl = (int*)p;    p += 64 * 4;
    // contiguous zero-region: sums | counts | deg | cursor
    char* zbase = p;
    float* sums   = (float*)p; p += (size_t)NUM_GRAPHS * HID * 4;
    float* counts = (float*)p; p += (size_t)NUM_GRAPHS * 4;
    int* deg    = (int*)p;  p += (size_t)N_NODES * 4;
    int* cursor = (int*)p;  p += (size_t)N_NODES * 4;
    size_t zbytes = (size_t)(p - zbase);

    hipMemsetAsync(zbase, 0, zbytes, stream);

    int eb = (E_TOT + 255) / 256;
    count_deg<<<eb, 256, 0, stream>>>(dstI, deg);
    block_sums<<<NB, 256, 0, stream>>>(deg, bsum);
    scan_partials<<<1, 64, 0, stream>>>(bsum, excl, offs);
    write_offs<<<NB, 256, 0, stream>>>(deg, excl, offs);
    scatter_edges<<<eb, 256, 0, stream>>>(srcI, dstI, offs, cursor, csr);

    int gemmGrid = (N_NODES + 31) / 32;
    int aggGrid  = (N_NODES * 32) / 256;   // exact: 6250

    // layer 1
    gemm_alpha<IN0><<<gemmGrid, 256, 0, stream>>>(x, W1, as1, ad1, h0, As, Ad);
    aggregate<<<aggGrid, 256, 0, stream>>>(h0, As, Ad, offs, csr, b1, h1, 1);
    // layer 2
    gemm_alpha<HID><<<gemmGrid, 256, 0, stream>>>(h1, W2, as2, ad2, h0, As, Ad);
    aggregate<<<aggGrid, 256, 0, stream>>>(h0, As, Ad, offs, csr, b2, h1, 1);
    // layer 3
    gemm_alpha<HID><<<gemmGrid, 256, 0, stream>>>(h1, W3, as3, ad3, h0, As, Ad);
    aggregate<<<aggGrid, 256, 0, stream>>>(h0, As, Ad, offs, csr, b3, h1, 0);

    // mean pool
    int teams = (N_NODES + 31) / 32;
    pool_sum<<<(teams * 32 + 255) / 256, 256, 0, stream>>>(h1, batch, sums, counts);
    finalize<<<(NUM_GRAPHS * HID + 255) / 256, 256, 0, stream>>>(sums, counts, out);
}